// Round 12
// baseline (40.398 us; speedup 1.0000x reference)
//
#include <hip/hip_runtime.h>

// ExpertMLP R12: 3-node structure; gemm tiles 32x32 -> 64x32 (tall):
// B L2 traffic = M-tiles x |W| halves (128->64 MB/layer), load instrs -25%.
// 256 blocks (16 mt x 16 nt), 8 expert-waves, K=512/wave, 128 MFMA/wave.
//  n1 prep:  x -> xbp; w1 -> w1p; w2 -> w2p (packed bf16)
//  n2 gemm1: hb packed bf16 + col stat partials [16][512]
//  n3 gemm2: BN params; hb -> BN+ELU -> As (64KB LDS); MFMA; blend -> out
// Packed layout: chunk(g,s,c,ri) at ((g*16+s)*64 + c*16 + ri)*8 elems;
// row = g*16+ri, k = s*32+c*8+j. Fragment (g,s) load = base + lane*16B.

typedef short bf16x8 __attribute__((ext_vector_type(8)));
typedef float f32x4 __attribute__((ext_vector_type(4)));
typedef unsigned short u16;
typedef u16 u16x4 __attribute__((ext_vector_type(4)));
typedef u16 u16x8 __attribute__((ext_vector_type(8)));

__device__ __forceinline__ u16 f2bf(float f) {
  union { float f; unsigned u; } v; v.f = f;
  return (u16)((v.u + 0x7FFFu + ((v.u >> 16) & 1u)) >> 16);  // RNE
}
__device__ __forceinline__ float bf2f(u16 u) {
  union { unsigned u; float f; } v; v.u = (unsigned)u << 16; return v.f;
}

// ---------------- n1: x pack + w1/w2 transpose-pack (R7-proven) -------------
__global__ __launch_bounds__(256) void prep_kernel(
    const float* __restrict__ x, const float* __restrict__ w1,
    const float* __restrict__ w2, u16* __restrict__ xbp,
    u16* __restrict__ w1p, u16* __restrict__ w2p)
{
  int bid = blockIdx.x, t = threadIdx.x;
  __shared__ float ld[64][65];               // +1 pad breaks col-read conflicts
  if (bid < 64) {                            // pack x (row-panel g = bid)
    int g = bid, ri = t & 15, q = t >> 4;
    #pragma unroll
    for (int rep = 0; rep < 4; ++rep) {
      int chunk = rep * 16 + q;              // (s,c)
      int s = chunk >> 2, c = chunk & 3;
      const float* src = x + (size_t)(g * 16 + ri) * 512 + s * 32 + c * 8;
      f32x4 v0 = *(const f32x4*)src;
      f32x4 v1 = *(const f32x4*)(src + 4);
      u16x8 o;
      #pragma unroll
      for (int i = 0; i < 4; ++i) { o[i] = f2bf(v0[i]); o[4 + i] = f2bf(v1[i]); }
      *(u16x8*)(xbp + ((size_t)(g * 16 + s) * 64 + c * 16 + ri) * 8) = o;
    }
    return;
  }
  int job = bid - 64;                        // 1024 jobs: 2 weights * 8 e * 64 tiles
  const float* src = (job >> 9) ? w2 : w1;
  u16* dst = (job >> 9) ? w2p : w1p;
  int rem = job & 511, e = rem >> 6, tl = rem & 63;
  int kt = tl >> 3, nt = tl & 7;             // source 64x64 tile at (kt,nt)
  #pragma unroll
  for (int j = 0; j < 4; ++j) {              // read [k][n] coalesced
    int kr = j * 16 + (t >> 4), nc = (t & 15) * 4;
    f32x4 v = *(const f32x4*)(src + (size_t)(e * 512 + kt * 64 + kr) * 512 + nt * 64 + nc);
    ld[kr][nc] = v.x; ld[kr][nc + 1] = v.y; ld[kr][nc + 2] = v.z; ld[kr][nc + 3] = v.w;
  }
  __syncthreads();
  #pragma unroll
  for (int rep = 0; rep < 2; ++rep) {        // packed write: 1KB runs, coalesced
    int gidx = rep * 256 + t;
    int ri = gidx & 15, c = (gidx >> 4) & 3, sl = (gidx >> 6) & 1, grp = gidx >> 7;
    int n_local = grp * 16 + ri;
    int gn = nt * 4 + grp, s = kt * 2 + sl, k0 = sl * 32 + c * 8;
    u16x8 o;
    #pragma unroll
    for (int i = 0; i < 8; ++i) o[i] = f2bf(ld[k0 + i][n_local]);
    *(u16x8*)(dst + ((size_t)((e * 32 + gn) * 16 + s) * 64 + c * 16 + ri) * 8) = o;
  }
}

// ---------------- n2: gemm1, 64x32 tile, 256 blocks, 8 expert-waves ---------
__global__ __launch_bounds__(512, 2) void gemm1_kernel(
    const u16* __restrict__ Ap, const u16* __restrict__ Wp,
    const float* __restrict__ coef, const float* __restrict__ bias,
    u16* __restrict__ hb, float* __restrict__ sP, float* __restrict__ qP)
{
  __shared__ __align__(16) char smem[38912]; // red 4*2304*4=36864 + parts 2048
  float* red = (float*)smem;                 // slot stride 2304 f32 ([64][36])
  f32x4* partS = (f32x4*)(smem + 36864);     // [8 waves][8 colgrp]
  f32x4* partQ = (f32x4*)(smem + 36864 + 1024);
  int raw = blockIdx.x, nt = raw & 15, mt = raw >> 4;  // same-nt -> same XCD
  int t = threadIdx.x, l = t & 63, e = t >> 6;

  const u16* Ab = Ap + (size_t)(mt * 4) * 16 * 512 + l * 8;           // g=mt*4+m
  const u16* Bb = Wp + (size_t)(e * 32 + nt * 2) * 16 * 512 + l * 8;  // gn=nt*2+n

  f32x4 acc[4][2] = {};
  bf16x8 bfr[2][2];
  #pragma unroll
  for (int n = 0; n < 2; ++n)                // B preload step 0
    bfr[0][n] = *(const bf16x8*)(Bb + (size_t)n * 16 * 512);

  #pragma unroll
  for (int s = 0; s < 16; ++s) {             // static dbuf idx
    const int cur = s & 1, nxt = cur ^ 1;
    if (s < 15) {
      #pragma unroll
      for (int n = 0; n < 2; ++n)            // prefetch next B (coalesced, L2)
        bfr[nxt][n] = *(const bf16x8*)(Bb + (size_t)n * 16 * 512 + (s + 1) * 512);
    }
    bf16x8 af[4];
    #pragma unroll
    for (int m = 0; m < 4; ++m)              // A fragments (coalesced, L1-hot)
      af[m] = *(const bf16x8*)(Ab + (size_t)m * 16 * 512 + s * 512);
    #pragma unroll
    for (int m = 0; m < 4; ++m)
      #pragma unroll
      for (int n = 0; n < 2; ++n)
        acc[m][n] = __builtin_amdgcn_mfma_f32_16x16x32_bf16(af[m], bfr[cur][n], acc[m][n], 0, 0, 0);
  }

  int rl = (l >> 4) * 4;
  #pragma unroll
  for (int m = 0; m < 4; ++m)                // coef scale (C/D row=(l>>4)*4+r+16m)
    #pragma unroll
    for (int r = 0; r < 4; ++r) {
      float cf = coef[(size_t)(mt * 64 + m * 16 + rl + r) * 8 + e];
      #pragma unroll
      for (int n = 0; n < 2; ++n) acc[m][n][r] *= cf;
    }

#define RED_STORE(slot)                                                       \
  { _Pragma("unroll") for (int m = 0; m < 4; ++m)                             \
    _Pragma("unroll") for (int n = 0; n < 2; ++n)                             \
    _Pragma("unroll") for (int r = 0; r < 4; ++r)                             \
      red[(slot) * 2304 + (m * 16 + rl + r) * 36 + n * 16 + (l & 15)] = acc[m][n][r]; }
#define RED_ADD(slot)                                                         \
  { _Pragma("unroll") for (int m = 0; m < 4; ++m)                             \
    _Pragma("unroll") for (int n = 0; n < 2; ++n)                             \
    _Pragma("unroll") for (int r = 0; r < 4; ++r)                             \
      acc[m][n][r] += red[(slot) * 2304 + (m * 16 + rl + r) * 36 + n * 16 + (l & 15)]; }

  if (e >= 4) RED_STORE(e - 4);              // 2-barrier reduce to 4 slots
  __syncthreads();
  if (e < 4) { RED_ADD(e); RED_STORE(e); }
  __syncthreads();

  {                                          // parallel epilogue: all 512 thr
    int row = t >> 3, c0 = (t & 7) * 4, w = t >> 6;
    f32x4 v = {0.f, 0.f, 0.f, 0.f};
    #pragma unroll
    for (int sl = 0; sl < 4; ++sl)
      v += *(const f32x4*)&red[sl * 2304 + row * 36 + c0];
    int rowg = mt * 64 + row, colg = nt * 32 + c0;
    f32x4 cv0 = *(const f32x4*)(coef + (size_t)rowg * 8);
    f32x4 cv1 = *(const f32x4*)(coef + (size_t)rowg * 8 + 4);
    #pragma unroll
    for (int e2 = 0; e2 < 4; ++e2) {
      v += cv0[e2] * *(const f32x4*)(bias + e2 * 512 + colg);
      v += cv1[e2] * *(const f32x4*)(bias + (e2 + 4) * 512 + colg);
    }
    f32x4 ss = v, qq = v * v;                // sum wave's 8 rows (xor row bits)
    #pragma unroll
    for (int i = 0; i < 4; ++i) {
      ss[i] += __shfl_xor(ss[i], 8);  qq[i] += __shfl_xor(qq[i], 8);
      ss[i] += __shfl_xor(ss[i], 16); qq[i] += __shfl_xor(qq[i], 16);
      ss[i] += __shfl_xor(ss[i], 32); qq[i] += __shfl_xor(qq[i], 32);
    }
    if (l < 8) { partS[w * 8 + l] = ss; partQ[w * 8 + l] = qq; }
    u16x4 o;                                 // hb packed write (8B)
    #pragma unroll
    for (int i = 0; i < 4; ++i) o[i] = f2bf(v[i]);
    int g = mt * 4 + (row >> 4), ri = row & 15;
    int cpk = c0 >> 3, j = c0 & 7;           // s == nt (tile spans one 32-col grp)
    *(u16x4*)(hb + ((size_t)(g * 16 + nt) * 64 + cpk * 16 + ri) * 8 + j) = o;
  }
  __syncthreads();
  if (t < 8) {                               // final stats partial (slot [mt])
    f32x4 S = {0.f, 0.f, 0.f, 0.f}, Q = {0.f, 0.f, 0.f, 0.f};
    #pragma unroll
    for (int w = 0; w < 8; ++w) { S += partS[w * 8 + t]; Q += partQ[w * 8 + t]; }
    *(f32x4*)(sP + mt * 512 + nt * 32 + t * 4) = S;
    *(f32x4*)(qP + mt * 512 + nt * 32 + t * 4) = Q;
  }
#undef RED_STORE
#undef RED_ADD
}

// ---------------- n3: gemm2, 64x32 tile, fused BN+ELU A-staging -------------
__global__ __launch_bounds__(512, 2) void gemm2_kernel(
    const u16* __restrict__ hb, const u16* __restrict__ Wp,
    const float* __restrict__ coef, const float* __restrict__ bias,
    const float* __restrict__ gamma, const float* __restrict__ beta,
    const float* __restrict__ sP, const float* __restrict__ qP,
    float* __restrict__ Out)
{
  __shared__ __align__(16) char smem[65536]; // As 64KB union red 36.9KB
  __shared__ float sc[512], sh[512];
  u16* As = (u16*)smem;
  float* red = (float*)smem;
  int raw = blockIdx.x, nt = raw & 15, mt = raw >> 4;
  int t = threadIdx.x, l = t & 63, e = t >> 6;

  const u16* Bb = Wp + (size_t)(e * 32 + nt * 2) * 16 * 512 + l * 8;
  bf16x8 bfr[2][2];
  #pragma unroll
  for (int n = 0; n < 2; ++n)                // B preload step 0 (issue early)
    bfr[0][n] = *(const bf16x8*)(Bb + (size_t)n * 16 * 512);

  {                                          // BN params: one col per thread
    float S = 0.f, Q = 0.f;
    #pragma unroll
    for (int p = 0; p < 16; ++p) { S += sP[p * 512 + t]; Q += qP[p * 512 + t]; }
    float mean = S * (1.0f / 1024.0f);
    float var  = Q * (1.0f / 1024.0f) - mean * mean;     // biased, matches ref
    float s_ = gamma[t] * rsqrtf(var + 1e-5f);
    sc[t] = s_; sh[t] = beta[t] - mean * s_;
  }
  __syncthreads();

  const u16* hsrc = hb + (size_t)mt * 32768; // this block's 64x512 slab (packed)
  #pragma unroll
  for (int rep = 0; rep < 8; ++rep) {        // BN+ELU transform -> As (linear)
    int ci = rep * 512 + t;                  // slab chunk id (4096 total)
    u16x8 hv = *(const u16x8*)(hsrc + (size_t)ci * 8);
    int s = (ci >> 6) & 15, c = (l >> 4) & 3;
    int k0 = s * 32 + c * 8;
    f32x4 s0 = *(const f32x4*)&sc[k0], s1 = *(const f32x4*)&sc[k0 + 4];
    f32x4 h0 = *(const f32x4*)&sh[k0], h1 = *(const f32x4*)&sh[k0 + 4];
    u16x8 o;
    #pragma unroll
    for (int i = 0; i < 4; ++i) {
      float v = bf2f(hv[i]) * s0[i] + h0[i];
      o[i] = f2bf(v > 0.f ? v : expm1f(v));
    }
    #pragma unroll
    for (int i = 0; i < 4; ++i) {
      float v = bf2f(hv[4 + i]) * s1[i] + h1[i];
      o[4 + i] = f2bf(v > 0.f ? v : expm1f(v));
    }
    *(u16x8*)&As[(size_t)ci * 8] = o;
  }
  __syncthreads();

  f32x4 acc[4][2] = {};
  #pragma unroll
  for (int s = 0; s < 16; ++s) {
    const int cur = s & 1, nxt = cur ^ 1;
    if (s < 15) {
      #pragma unroll
      for (int n = 0; n < 2; ++n)
        bfr[nxt][n] = *(const bf16x8*)(Bb + (size_t)n * 16 * 512 + (s + 1) * 512);
    }
    bf16x8 af[4];
    #pragma unroll
    for (int m = 0; m < 4; ++m)              // A from LDS, lane-linear (1KB runs)
      af[m] = *(const bf16x8*)&As[((m * 16 + s) * 64 + l) * 8];
    #pragma unroll
    for (int m = 0; m < 4; ++m)
      #pragma unroll
      for (int n = 0; n < 2; ++n)
        acc[m][n] = __builtin_amdgcn_mfma_f32_16x16x32_bf16(af[m], bfr[cur][n], acc[m][n], 0, 0, 0);
  }
  __syncthreads();                           // As -> red reuse barrier

  int rl = (l >> 4) * 4;
  #pragma unroll
  for (int m = 0; m < 4; ++m)
    #pragma unroll
    for (int r = 0; r < 4; ++r) {
      float cf = coef[(size_t)(mt * 64 + m * 16 + rl + r) * 8 + e];
      #pragma unroll
      for (int n = 0; n < 2; ++n) acc[m][n][r] *= cf;
    }

#define RED_STORE(slot)                                                       \
  { _Pragma("unroll") for (int m = 0; m < 4; ++m)                             \
    _Pragma("unroll") for (int n = 0; n < 2; ++n)                             \
    _Pragma("unroll") for (int r = 0; r < 4; ++r)                             \
      red[(slot) * 2304 + (m * 16 + rl + r) * 36 + n * 16 + (l & 15)] = acc[m][n][r]; }
#define RED_ADD(slot)                                                         \
  { _Pragma("unroll") for (int m = 0; m < 4; ++m)                             \
    _Pragma("unroll") for (int n = 0; n < 2; ++n)                             \
    _Pragma("unroll") for (int r = 0; r < 4; ++r)                             \
      acc[m][n][r] += red[(slot) * 2304 + (m * 16 + rl + r) * 36 + n * 16 + (l & 15)]; }

  if (e >= 4) RED_STORE(e - 4);
  __syncthreads();
  if (e < 4) { RED_ADD(e); RED_STORE(e); }
  __syncthreads();

  {                                          // parallel epilogue -> out
    int row = t >> 3, c0 = (t & 7) * 4;
    f32x4 v = {0.f, 0.f, 0.f, 0.f};
    #pragma unroll
    for (int sl = 0; sl < 4; ++sl)
      v += *(const f32x4*)&red[sl * 2304 + row * 36 + c0];
    int rowg = mt * 64 + row, colg = nt * 32 + c0;
    f32x4 cv0 = *(const f32x4*)(coef + (size_t)rowg * 8);
    f32x4 cv1 = *(const f32x4*)(coef + (size_t)rowg * 8 + 4);
    #pragma unroll
    for (int e2 = 0; e2 < 4; ++e2) {
      v += cv0[e2] * *(const f32x4*)(bias + e2 * 512 + colg);
      v += cv1[e2] * *(const f32x4*)(bias + (e2 + 4) * 512 + colg);
    }
    *(f32x4*)(Out + (size_t)rowg * 512 + colg) = v;
  }
#undef RED_STORE
#undef RED_ADD
}

extern "C" void kernel_launch(void* const* d_in, const int* in_sizes, int n_in,
                              void* d_out, int out_size, void* d_ws, size_t ws_size,
                              hipStream_t stream)
{
  const float* x     = (const float*)d_in[0];
  const float* coef  = (const float*)d_in[1];
  const float* w1    = (const float*)d_in[2];
  const float* b1    = (const float*)d_in[3];
  const float* w2    = (const float*)d_in[4];
  const float* b2    = (const float*)d_in[5];
  const float* gamma = (const float*)d_in[6];
  const float* beta  = (const float*)d_in[7];
  float* out = (float*)d_out;

  char* ws = (char*)d_ws;
  u16* w1p  = (u16*)(ws);                          //  4 MB packed bf16
  u16* w2p  = (u16*)(ws + (4u << 20));             //  4 MB
  u16* xbp  = (u16*)(ws + (8u << 20));             //  1 MB packed bf16
  u16* hb   = (u16*)(ws + (9u << 20));             //  1 MB packed bf16 (pre-BN h)
  float* sP = (float*)(ws + (10u << 20));          // 32 KB [16][512] col sums
  float* qP = (float*)(ws + (10u << 20) + 32768);  // 32 KB [16][512] col sumsq

  prep_kernel<<<1088, 256, 0, stream>>>(x, w1, w2, xbp, w1p, w2p);
  gemm1_kernel<<<256, 512, 0, stream>>>(xbp, w1p, coef, b1, hb, sP, qP);
  gemm2_kernel<<<256, 512, 0, stream>>>(hb, w2p, coef, b2, gamma, beta, sP, qP, out);
}

// Round 13
// 36.306 us; speedup vs baseline: 1.1127x; 1.1127x over previous
//
#include <hip/hip_runtime.h>

// ExpertMLP R13: R11 (best, 38.0us) + gemm1 A-LDS staging: the 8 expert-waves
// previously each loaded the SAME A fragments from global (8x redundant; half
// of gemm1's load bytes). Now the block stages its 32-row packed A slab (32KB)
// into LDS once; fragments are lane-linear ds_read_b128. gemm2 already did this.
//  n1 prep:  x -> xbp; w1 -> w1p; w2 -> w2p (packed bf16)
//  n2 gemm1: 512 blocks 32x32, hb packed bf16 + col stat partials
//  n3 gemm2: BN params; hb -> BN+ELU -> As (LDS); MFMA; blend -> out
// Packed layout: chunk(g,s,c,ri) at ((g*16+s)*64 + c*16 + ri)*8 elems;
// row = g*16+ri, k = s*32+c*8+j. Fragment (g,s) load = base + lane*16B.

typedef short bf16x8 __attribute__((ext_vector_type(8)));
typedef float f32x4 __attribute__((ext_vector_type(4)));
typedef unsigned short u16;
typedef u16 u16x4 __attribute__((ext_vector_type(4)));
typedef u16 u16x8 __attribute__((ext_vector_type(8)));

__device__ __forceinline__ u16 f2bf(float f) {
  union { float f; unsigned u; } v; v.f = f;
  return (u16)((v.u + 0x7FFFu + ((v.u >> 16) & 1u)) >> 16);  // RNE
}
__device__ __forceinline__ float bf2f(u16 u) {
  union { unsigned u; float f; } v; v.u = (unsigned)u << 16; return v.f;
}

// ---------------- n1: x pack + w1/w2 transpose-pack (R7-proven) -------------
__global__ __launch_bounds__(256) void prep_kernel(
    const float* __restrict__ x, const float* __restrict__ w1,
    const float* __restrict__ w2, u16* __restrict__ xbp,
    u16* __restrict__ w1p, u16* __restrict__ w2p)
{
  int bid = blockIdx.x, t = threadIdx.x;
  __shared__ float ld[64][65];               // +1 pad breaks col-read conflicts
  if (bid < 64) {                            // pack x (row-panel g = bid)
    int g = bid, ri = t & 15, q = t >> 4;
    #pragma unroll
    for (int rep = 0; rep < 4; ++rep) {
      int chunk = rep * 16 + q;              // (s,c)
      int s = chunk >> 2, c = chunk & 3;
      const float* src = x + (size_t)(g * 16 + ri) * 512 + s * 32 + c * 8;
      f32x4 v0 = *(const f32x4*)src;
      f32x4 v1 = *(const f32x4*)(src + 4);
      u16x8 o;
      #pragma unroll
      for (int i = 0; i < 4; ++i) { o[i] = f2bf(v0[i]); o[4 + i] = f2bf(v1[i]); }
      *(u16x8*)(xbp + ((size_t)(g * 16 + s) * 64 + c * 16 + ri) * 8) = o;
    }
    return;
  }
  int job = bid - 64;                        // 1024 jobs: 2 weights * 8 e * 64 tiles
  const float* src = (job >> 9) ? w2 : w1;
  u16* dst = (job >> 9) ? w2p : w1p;
  int rem = job & 511, e = rem >> 6, tl = rem & 63;
  int kt = tl >> 3, nt = tl & 7;             // source 64x64 tile at (kt,nt)
  #pragma unroll
  for (int j = 0; j < 4; ++j) {              // read [k][n] coalesced
    int kr = j * 16 + (t >> 4), nc = (t & 15) * 4;
    f32x4 v = *(const f32x4*)(src + (size_t)(e * 512 + kt * 64 + kr) * 512 + nt * 64 + nc);
    ld[kr][nc] = v.x; ld[kr][nc + 1] = v.y; ld[kr][nc + 2] = v.z; ld[kr][nc + 3] = v.w;
  }
  __syncthreads();
  #pragma unroll
  for (int rep = 0; rep < 2; ++rep) {        // packed write: 1KB runs, coalesced
    int gidx = rep * 256 + t;
    int ri = gidx & 15, c = (gidx >> 4) & 3, sl = (gidx >> 6) & 1, grp = gidx >> 7;
    int n_local = grp * 16 + ri;
    int gn = nt * 4 + grp, s = kt * 2 + sl, k0 = sl * 32 + c * 8;
    u16x8 o;
    #pragma unroll
    for (int i = 0; i < 8; ++i) o[i] = f2bf(ld[k0 + i][n_local]);
    *(u16x8*)(dst + ((size_t)((e * 32 + gn) * 16 + s) * 64 + c * 16 + ri) * 8) = o;
  }
}

// ---------------- n2: gemm1, 32x32 tile, 512 blocks, A staged in LDS --------
__global__ __launch_bounds__(512, 4) void gemm1_kernel(
    const u16* __restrict__ Ap, const u16* __restrict__ Wp,
    const float* __restrict__ coef, const float* __restrict__ bias,
    u16* __restrict__ hb, float* __restrict__ sP, float* __restrict__ qP)
{
  __shared__ __align__(16) char smem[52224]; // As 32768 | red 18432 | parts 1024
  u16* As = (u16*)smem;                      // packed A slab (32 rows x 512 k)
  float* red = (float*)(smem + 32768);       // 4 slots x [32][36]
  f32x4* partS = (f32x4*)(smem + 32768 + 18432);
  f32x4* partQ = partS + 32;
  int raw = blockIdx.x, nt = raw & 15, mt = raw >> 4;
  int t = threadIdx.x, l = t & 63, e = t >> 6;

  const u16* Bb = Wp + (size_t)(e * 32 + nt * 2) * 16 * 512 + l * 8;
  bf16x8 bfr[2][2];
  #pragma unroll
  for (int n = 0; n < 2; ++n)                // B preload step 0 (issue early)
    bfr[0][n] = *(const bf16x8*)(Bb + (size_t)n * 16 * 512);

  const u16* Aslab = Ap + (size_t)(mt * 2) * 16 * 512;   // 16384 elems = 32 KB
  #pragma unroll
  for (int rep = 0; rep < 4; ++rep) {        // stage A once: coalesced 16B/thr
    int ci = rep * 512 + t;
    *(u16x8*)&As[(size_t)ci * 8] = *(const u16x8*)(Aslab + (size_t)ci * 8);
  }
  __syncthreads();

  f32x4 acc[2][2] = {};
  #pragma unroll
  for (int s = 0; s < 16; ++s) {             // static dbuf idx
    const int cur = s & 1, nxt = cur ^ 1;
    if (s < 15) {
      #pragma unroll
      for (int n = 0; n < 2; ++n)            // prefetch next B (coalesced, L2)
        bfr[nxt][n] = *(const bf16x8*)(Bb + (size_t)n * 16 * 512 + (s + 1) * 512);
    }
    bf16x8 af[2];
    #pragma unroll
    for (int m = 0; m < 2; ++m)              // A from LDS, lane-linear (free)
      af[m] = *(const bf16x8*)&As[((m * 16 + s) * 64 + l) * 8];
    #pragma unroll
    for (int m = 0; m < 2; ++m)
      #pragma unroll
      for (int n = 0; n < 2; ++n)
        acc[m][n] = __builtin_amdgcn_mfma_f32_16x16x32_bf16(af[m], bfr[cur][n], acc[m][n], 0, 0, 0);
  }

  int rl = (l >> 4) * 4;
  #pragma unroll
  for (int m = 0; m < 2; ++m)                // coef scale (C/D row=(l>>4)*4+r+16m)
    #pragma unroll
    for (int r = 0; r < 4; ++r) {
      float cf = coef[(size_t)(mt * 32 + m * 16 + rl + r) * 8 + e];
      #pragma unroll
      for (int n = 0; n < 2; ++n) acc[m][n][r] *= cf;
    }

#define RED_STORE(slot)                                                       \
  { _Pragma("unroll") for (int m = 0; m < 2; ++m)                             \
    _Pragma("unroll") for (int n = 0; n < 2; ++n)                             \
    _Pragma("unroll") for (int r = 0; r < 4; ++r)                             \
      red[(slot) * 1152 + (m * 16 + rl + r) * 36 + n * 16 + (l & 15)] = acc[m][n][r]; }
#define RED_ADD(slot)                                                         \
  { _Pragma("unroll") for (int m = 0; m < 2; ++m)                             \
    _Pragma("unroll") for (int n = 0; n < 2; ++n)                             \
    _Pragma("unroll") for (int r = 0; r < 4; ++r)                             \
      acc[m][n][r] += red[(slot) * 1152 + (m * 16 + rl + r) * 36 + n * 16 + (l & 15)]; }

  if (e >= 4) RED_STORE(e - 4);              // 2-barrier reduce to 4 slots
  __syncthreads();
  if (e < 4) { RED_ADD(e); RED_STORE(e); }
  __syncthreads();

  if (t < 256) {                             // parallel epilogue (8 f32x4/row)
    int row = t >> 3, c0 = (t & 7) * 4, w = t >> 6;
    f32x4 v = {0.f, 0.f, 0.f, 0.f};
    #pragma unroll
    for (int sl = 0; sl < 4; ++sl)
      v += *(const f32x4*)&red[sl * 1152 + row * 36 + c0];
    int rowg = mt * 32 + row, colg = nt * 32 + c0;
    f32x4 cv0 = *(const f32x4*)(coef + (size_t)rowg * 8);
    f32x4 cv1 = *(const f32x4*)(coef + (size_t)rowg * 8 + 4);
    #pragma unroll
    for (int e2 = 0; e2 < 4; ++e2) {
      v += cv0[e2] * *(const f32x4*)(bias + e2 * 512 + colg);
      v += cv1[e2] * *(const f32x4*)(bias + (e2 + 4) * 512 + colg);
    }
    f32x4 ss = v, qq = v * v;                // sum this wave's 8 rows (xor r-bits)
    #pragma unroll
    for (int i = 0; i < 4; ++i) {
      ss[i] += __shfl_xor(ss[i], 8);  qq[i] += __shfl_xor(qq[i], 8);
      ss[i] += __shfl_xor(ss[i], 16); qq[i] += __shfl_xor(qq[i], 16);
      ss[i] += __shfl_xor(ss[i], 32); qq[i] += __shfl_xor(qq[i], 32);
    }
    if (l < 8) { partS[w * 8 + l] = ss; partQ[w * 8 + l] = qq; }
    u16x4 o;                                 // hb packed write (8B)
    #pragma unroll
    for (int i = 0; i < 4; ++i) o[i] = f2bf(v[i]);
    int g = row >> 4, ri = row & 15;
    int cpk = (c0 >> 3) & 3, j = c0 & 7;     // s == nt (c0 < 32)
    *(u16x4*)(hb + ((size_t)((mt * 2 + g) * 16 + nt) * 64 + cpk * 16 + ri) * 8 + j) = o;
  }
  __syncthreads();
  if (t < 8) {                               // final stats partial (slot [mt])
    f32x4 S = partS[t] + partS[8 + t] + partS[16 + t] + partS[24 + t];
    f32x4 Q = partQ[t] + partQ[8 + t] + partQ[16 + t] + partQ[24 + t];
    *(f32x4*)(sP + mt * 512 + nt * 32 + t * 4) = S;
    *(f32x4*)(qP + mt * 512 + nt * 32 + t * 4) = Q;
  }
#undef RED_STORE
#undef RED_ADD
}

// ---------------- n3: gemm2, 32x32 tile, fused BN+ELU A-staging (R11) -------
__global__ __launch_bounds__(512, 4) void gemm2_kernel(
    const u16* __restrict__ hb, const u16* __restrict__ Wp,
    const float* __restrict__ coef, const float* __restrict__ bias,
    const float* __restrict__ gamma, const float* __restrict__ beta,
    const float* __restrict__ sP, const float* __restrict__ qP,
    float* __restrict__ Out)
{
  __shared__ __align__(16) char smem[32768]; // As 32KB union red 18.4KB
  __shared__ float sc[512], sh[512];
  u16* As = (u16*)smem;
  float* red = (float*)smem;
  int raw = blockIdx.x, nt = raw & 15, mt = raw >> 4;
  int t = threadIdx.x, l = t & 63, e = t >> 6;

  const u16* Bb = Wp + (size_t)(e * 32 + nt * 2) * 16 * 512 + l * 8;
  bf16x8 bfr[2][2];
  #pragma unroll
  for (int n = 0; n < 2; ++n)                // B preload step 0 (issue early)
    bfr[0][n] = *(const bf16x8*)(Bb + (size_t)n * 16 * 512);

  {                                          // BN params: one col per thread
    float S = 0.f, Q = 0.f;
    #pragma unroll
    for (int p = 0; p < 32; ++p) { S += sP[p * 512 + t]; Q += qP[p * 512 + t]; }
    float mean = S * (1.0f / 1024.0f);
    float var  = Q * (1.0f / 1024.0f) - mean * mean;     // biased, matches ref
    float s_ = gamma[t] * rsqrtf(var + 1e-5f);
    sc[t] = s_; sh[t] = beta[t] - mean * s_;
  }
  __syncthreads();

  const u16* hsrc = hb + (size_t)mt * 16384; // this block's 32x512 slab (packed)
  #pragma unroll
  for (int rep = 0; rep < 4; ++rep) {        // BN+ELU transform -> As (linear)
    int ci = rep * 512 + t;
    u16x8 hv = *(const u16x8*)(hsrc + (size_t)ci * 8);
    int s = (ci >> 6) & 15, c = (l >> 4) & 3;
    int k0 = s * 32 + c * 8;
    f32x4 s0 = *(const f32x4*)&sc[k0], s1 = *(const f32x4*)&sc[k0 + 4];
    f32x4 h0 = *(const f32x4*)&sh[k0], h1 = *(const f32x4*)&sh[k0 + 4];
    u16x8 o;
    #pragma unroll
    for (int i = 0; i < 4; ++i) {
      float v = bf2f(hv[i]) * s0[i] + h0[i];
      o[i] = f2bf(v > 0.f ? v : expm1f(v));
    }
    #pragma unroll
    for (int i = 0; i < 4; ++i) {
      float v = bf2f(hv[4 + i]) * s1[i] + h1[i];
      o[4 + i] = f2bf(v > 0.f ? v : expm1f(v));
    }
    *(u16x8*)&As[(size_t)ci * 8] = o;
  }
  __syncthreads();

  f32x4 acc[2][2] = {};
  #pragma unroll
  for (int s = 0; s < 16; ++s) {
    const int cur = s & 1, nxt = cur ^ 1;
    if (s < 15) {
      #pragma unroll
      for (int n = 0; n < 2; ++n)
        bfr[nxt][n] = *(const bf16x8*)(Bb + (size_t)n * 16 * 512 + (s + 1) * 512);
    }
    bf16x8 af[2];
    #pragma unroll
    for (int m = 0; m < 2; ++m)              // A from LDS, lane-linear
      af[m] = *(const bf16x8*)&As[((m * 16 + s) * 64 + l) * 8];
    #pragma unroll
    for (int m = 0; m < 2; ++m)
      #pragma unroll
      for (int n = 0; n < 2; ++n)
        acc[m][n] = __builtin_amdgcn_mfma_f32_16x16x32_bf16(af[m], bfr[cur][n], acc[m][n], 0, 0, 0);
  }
  __syncthreads();                           // As -> red reuse barrier

  int rl = (l >> 4) * 4;
  #pragma unroll
  for (int m = 0; m < 2; ++m)
    #pragma unroll
    for (int r = 0; r < 4; ++r) {
      float cf = coef[(size_t)(mt * 32 + m * 16 + rl + r) * 8 + e];
      #pragma unroll
      for (int n = 0; n < 2; ++n) acc[m][n][r] *= cf;
    }

#define RED_STORE(slot)                                                       \
  { _Pragma("unroll") for (int m = 0; m < 2; ++m)                             \
    _Pragma("unroll") for (int n = 0; n < 2; ++n)                             \
    _Pragma("unroll") for (int r = 0; r < 4; ++r)                             \
      red[(slot) * 1152 + (m * 16 + rl + r) * 36 + n * 16 + (l & 15)] = acc[m][n][r]; }
#define RED_ADD(slot)                                                         \
  { _Pragma("unroll") for (int m = 0; m < 2; ++m)                             \
    _Pragma("unroll") for (int n = 0; n < 2; ++n)                             \
    _Pragma("unroll") for (int r = 0; r < 4; ++r)                             \
      acc[m][n][r] += red[(slot) * 1152 + (m * 16 + rl + r) * 36 + n * 16 + (l & 15)]; }

  if (e >= 4) RED_STORE(e - 4);
  __syncthreads();
  if (e < 4) { RED_ADD(e); RED_STORE(e); }
  __syncthreads();

  if (t < 256) {                             // parallel epilogue -> out
    int row = t >> 3, c0 = (t & 7) * 4;
    f32x4 v = {0.f, 0.f, 0.f, 0.f};
    #pragma unroll
    for (int sl = 0; sl < 4; ++sl)
      v += *(const f32x4*)&red[sl * 1152 + row * 36 + c0];
    int rowg = mt * 32 + row, colg = nt * 32 + c0;
    f32x4 cv0 = *(const f32x4*)(coef + (size_t)rowg * 8);
    f32x4 cv1 = *(const f32x4*)(coef + (size_t)rowg * 8 + 4);
    #pragma unroll
    for (int e2 = 0; e2 < 4; ++e2) {
      v += cv0[e2] * *(const f32x4*)(bias + e2 * 512 + colg);
      v += cv1[e2] * *(const f32x4*)(bias + (e2 + 4) * 512 + colg);
    }
    *(f32x4*)(Out + (size_t)rowg * 512 + colg) = v;
  }
#undef RED_STORE
#undef RED_ADD
}

extern "C" void kernel_launch(void* const* d_in, const int* in_sizes, int n_in,
                              void* d_out, int out_size, void* d_ws, size_t ws_size,
                              hipStream_t stream)
{
  const float* x     = (const float*)d_in[0];
  const float* coef  = (const float*)d_in[1];
  const float* w1    = (const float*)d_in[2];
  const float* b1    = (const float*)d_in[3];
  const float* w2    = (const float*)d_in[4];
  const float* b2    = (const float*)d_in[5];
  const float* gamma = (const float*)d_in[6];
  const float* beta  = (const float*)d_in[7];
  float* out = (float*)d_out;

  char* ws = (char*)d_ws;
  u16* w1p  = (u16*)(ws);                          //  4 MB packed bf16
  u16* w2p  = (u16*)(ws + (4u << 20));             //  4 MB
  u16* xbp  = (u16*)(ws + (8u << 20));             //  1 MB packed bf16
  u16* hb   = (u16*)(ws + (9u << 20));             //  1 MB packed bf16 (pre-BN h)
  float* sP = (float*)(ws + (10u << 20));          // 64 KB [32][512] col sums
  float* qP = (float*)(ws + (10u << 20) + 65536);  // 64 KB [32][512] col sumsq

  prep_kernel<<<1088, 256, 0, stream>>>(x, w1, w2, xbp, w1p, w2p);
  gemm1_kernel<<<512, 512, 0, stream>>>(xbp, w1p, coef, b1, hb, sP, qP);
  gemm2_kernel<<<512, 512, 0, stream>>>(hb, w2p, coef, b2, gamma, beta, sP, qP, out);
}

// Round 14
// 35.549 us; speedup vs baseline: 1.1364x; 1.0213x over previous
//
#include <hip/hip_runtime.h>

// ExpertMLP R14: R13 + gemm1 64x32 tall tile (B L2 traffic halves, 128->64 MB)
// now that A-LDS staging (R13) removed the A-redundancy that sank R12.
//  n1 prep:  x -> xbp; w1 -> w1p; w2 -> w2p (packed bf16)
//  n2 gemm1: 256 blocks 64x32, A slab 64KB in LDS, hb packed + stats [16][512]
//  n3 gemm2: BN params (16 partials); hb -> BN+ELU -> As; MFMA; blend -> out
// Packed layout: chunk(g,s,c,ri) at ((g*16+s)*64 + c*16 + ri)*8 elems;
// row = g*16+ri, k = s*32+c*8+j. Fragment (g,s) load = base + lane*16B.

typedef short bf16x8 __attribute__((ext_vector_type(8)));
typedef float f32x4 __attribute__((ext_vector_type(4)));
typedef unsigned short u16;
typedef u16 u16x4 __attribute__((ext_vector_type(4)));
typedef u16 u16x8 __attribute__((ext_vector_type(8)));

__device__ __forceinline__ u16 f2bf(float f) {
  union { float f; unsigned u; } v; v.f = f;
  return (u16)((v.u + 0x7FFFu + ((v.u >> 16) & 1u)) >> 16);  // RNE
}
__device__ __forceinline__ float bf2f(u16 u) {
  union { unsigned u; float f; } v; v.u = (unsigned)u << 16; return v.f;
}

// ---------------- n1: x pack + w1/w2 transpose-pack (R7-proven) -------------
__global__ __launch_bounds__(256) void prep_kernel(
    const float* __restrict__ x, const float* __restrict__ w1,
    const float* __restrict__ w2, u16* __restrict__ xbp,
    u16* __restrict__ w1p, u16* __restrict__ w2p)
{
  int bid = blockIdx.x, t = threadIdx.x;
  __shared__ float ld[64][65];               // +1 pad breaks col-read conflicts
  if (bid < 64) {                            // pack x (row-panel g = bid)
    int g = bid, ri = t & 15, q = t >> 4;
    #pragma unroll
    for (int rep = 0; rep < 4; ++rep) {
      int chunk = rep * 16 + q;              // (s,c)
      int s = chunk >> 2, c = chunk & 3;
      const float* src = x + (size_t)(g * 16 + ri) * 512 + s * 32 + c * 8;
      f32x4 v0 = *(const f32x4*)src;
      f32x4 v1 = *(const f32x4*)(src + 4);
      u16x8 o;
      #pragma unroll
      for (int i = 0; i < 4; ++i) { o[i] = f2bf(v0[i]); o[4 + i] = f2bf(v1[i]); }
      *(u16x8*)(xbp + ((size_t)(g * 16 + s) * 64 + c * 16 + ri) * 8) = o;
    }
    return;
  }
  int job = bid - 64;                        // 1024 jobs: 2 weights * 8 e * 64 tiles
  const float* src = (job >> 9) ? w2 : w1;
  u16* dst = (job >> 9) ? w2p : w1p;
  int rem = job & 511, e = rem >> 6, tl = rem & 63;
  int kt = tl >> 3, nt = tl & 7;             // source 64x64 tile at (kt,nt)
  #pragma unroll
  for (int j = 0; j < 4; ++j) {              // read [k][n] coalesced
    int kr = j * 16 + (t >> 4), nc = (t & 15) * 4;
    f32x4 v = *(const f32x4*)(src + (size_t)(e * 512 + kt * 64 + kr) * 512 + nt * 64 + nc);
    ld[kr][nc] = v.x; ld[kr][nc + 1] = v.y; ld[kr][nc + 2] = v.z; ld[kr][nc + 3] = v.w;
  }
  __syncthreads();
  #pragma unroll
  for (int rep = 0; rep < 2; ++rep) {        // packed write: 1KB runs, coalesced
    int gidx = rep * 256 + t;
    int ri = gidx & 15, c = (gidx >> 4) & 3, sl = (gidx >> 6) & 1, grp = gidx >> 7;
    int n_local = grp * 16 + ri;
    int gn = nt * 4 + grp, s = kt * 2 + sl, k0 = sl * 32 + c * 8;
    u16x8 o;
    #pragma unroll
    for (int i = 0; i < 8; ++i) o[i] = f2bf(ld[k0 + i][n_local]);
    *(u16x8*)(dst + ((size_t)((e * 32 + gn) * 16 + s) * 64 + c * 16 + ri) * 8) = o;
  }
}

// ---------------- n2: gemm1, 64x32 tile, 256 blocks, A slab in LDS ----------
__global__ __launch_bounds__(512, 2) void gemm1_kernel(
    const u16* __restrict__ Ap, const u16* __restrict__ Wp,
    const float* __restrict__ coef, const float* __restrict__ bias,
    u16* __restrict__ hb, float* __restrict__ sP, float* __restrict__ qP)
{
  __shared__ __align__(16) char smem[65536]; // As 64KB UNION red 36.9K+parts 2K
  u16* As = (u16*)smem;                      // packed A slab (64 rows x 512 k)
  float* red = (float*)smem;                 // 4 slots x [64][36] (after barrier)
  f32x4* partS = (f32x4*)(smem + 36864);     // [8 waves][8 colgrp]
  f32x4* partQ = partS + 64;
  int raw = blockIdx.x, nt = raw & 15, mt = raw >> 4;
  int t = threadIdx.x, l = t & 63, e = t >> 6;

  const u16* Bb = Wp + (size_t)(e * 32 + nt * 2) * 16 * 512 + l * 8;
  bf16x8 bfr[2][2];
  #pragma unroll
  for (int n = 0; n < 2; ++n)                // B preload step 0 (issue early)
    bfr[0][n] = *(const bf16x8*)(Bb + (size_t)n * 16 * 512);

  const u16* Aslab = Ap + (size_t)(mt * 4) * 16 * 512;   // 32768 elems = 64 KB
  #pragma unroll
  for (int rep = 0; rep < 8; ++rep) {        // stage A once: coalesced 16B/thr
    int ci = rep * 512 + t;
    *(u16x8*)&As[(size_t)ci * 8] = *(const u16x8*)(Aslab + (size_t)ci * 8);
  }
  __syncthreads();

  f32x4 acc[4][2] = {};
  #pragma unroll
  for (int s = 0; s < 16; ++s) {             // static dbuf idx
    const int cur = s & 1, nxt = cur ^ 1;
    if (s < 15) {
      #pragma unroll
      for (int n = 0; n < 2; ++n)            // prefetch next B (coalesced, L2)
        bfr[nxt][n] = *(const bf16x8*)(Bb + (size_t)n * 16 * 512 + (s + 1) * 512);
    }
    bf16x8 af[4];
    #pragma unroll
    for (int m = 0; m < 4; ++m)              // A from LDS, lane-linear (free)
      af[m] = *(const bf16x8*)&As[((m * 16 + s) * 64 + l) * 8];
    #pragma unroll
    for (int m = 0; m < 4; ++m)
      #pragma unroll
      for (int n = 0; n < 2; ++n)
        acc[m][n] = __builtin_amdgcn_mfma_f32_16x16x32_bf16(af[m], bfr[cur][n], acc[m][n], 0, 0, 0);
  }
  __syncthreads();                           // As dead; red may alias below

  int rl = (l >> 4) * 4;
  #pragma unroll
  for (int m = 0; m < 4; ++m)                // coef scale (C/D row=(l>>4)*4+r+16m)
    #pragma unroll
    for (int r = 0; r < 4; ++r) {
      float cf = coef[(size_t)(mt * 64 + m * 16 + rl + r) * 8 + e];
      #pragma unroll
      for (int n = 0; n < 2; ++n) acc[m][n][r] *= cf;
    }

#define RED_STORE(slot)                                                       \
  { _Pragma("unroll") for (int m = 0; m < 4; ++m)                             \
    _Pragma("unroll") for (int n = 0; n < 2; ++n)                             \
    _Pragma("unroll") for (int r = 0; r < 4; ++r)                             \
      red[(slot) * 2304 + (m * 16 + rl + r) * 36 + n * 16 + (l & 15)] = acc[m][n][r]; }
#define RED_ADD(slot)                                                         \
  { _Pragma("unroll") for (int m = 0; m < 4; ++m)                             \
    _Pragma("unroll") for (int n = 0; n < 2; ++n)                             \
    _Pragma("unroll") for (int r = 0; r < 4; ++r)                             \
      acc[m][n][r] += red[(slot) * 2304 + (m * 16 + rl + r) * 36 + n * 16 + (l & 15)]; }

  if (e >= 4) RED_STORE(e - 4);              // 2-barrier reduce to 4 slots
  __syncthreads();
  if (e < 4) { RED_ADD(e); RED_STORE(e); }
  __syncthreads();

  {                                          // parallel epilogue: all 512 thr
    int row = t >> 3, c0 = (t & 7) * 4, w = t >> 6;
    f32x4 v = {0.f, 0.f, 0.f, 0.f};
    #pragma unroll
    for (int sl = 0; sl < 4; ++sl)
      v += *(const f32x4*)&red[sl * 2304 + row * 36 + c0];
    int rowg = mt * 64 + row, colg = nt * 32 + c0;
    f32x4 cv0 = *(const f32x4*)(coef + (size_t)rowg * 8);
    f32x4 cv1 = *(const f32x4*)(coef + (size_t)rowg * 8 + 4);
    #pragma unroll
    for (int e2 = 0; e2 < 4; ++e2) {
      v += cv0[e2] * *(const f32x4*)(bias + e2 * 512 + colg);
      v += cv1[e2] * *(const f32x4*)(bias + (e2 + 4) * 512 + colg);
    }
    f32x4 ss = v, qq = v * v;                // sum wave's 8 rows (xor row bits)
    #pragma unroll
    for (int i = 0; i < 4; ++i) {
      ss[i] += __shfl_xor(ss[i], 8);  qq[i] += __shfl_xor(qq[i], 8);
      ss[i] += __shfl_xor(ss[i], 16); qq[i] += __shfl_xor(qq[i], 16);
      ss[i] += __shfl_xor(ss[i], 32); qq[i] += __shfl_xor(qq[i], 32);
    }
    if (l < 8) { partS[w * 8 + l] = ss; partQ[w * 8 + l] = qq; }
    u16x4 o;                                 // hb packed write (8B)
    #pragma unroll
    for (int i = 0; i < 4; ++i) o[i] = f2bf(v[i]);
    int g = mt * 4 + (row >> 4), ri = row & 15;
    int cpk = c0 >> 3, j = c0 & 7;           // s == nt (tile spans one 32-col grp)
    *(u16x4*)(hb + ((size_t)(g * 16 + nt) * 64 + cpk * 16 + ri) * 8 + j) = o;
  }
  __syncthreads();
  if (t < 8) {                               // final stats partial (slot [mt])
    f32x4 S = {0.f, 0.f, 0.f, 0.f}, Q = {0.f, 0.f, 0.f, 0.f};
    #pragma unroll
    for (int w = 0; w < 8; ++w) { S += partS[w * 8 + t]; Q += partQ[w * 8 + t]; }
    *(f32x4*)(sP + mt * 512 + nt * 32 + t * 4) = S;
    *(f32x4*)(qP + mt * 512 + nt * 32 + t * 4) = Q;
  }
#undef RED_STORE
#undef RED_ADD
}

// ---------------- n3: gemm2, 32x32 tile, fused BN+ELU A-staging (R13) -------
__global__ __launch_bounds__(512, 4) void gemm2_kernel(
    const u16* __restrict__ hb, const u16* __restrict__ Wp,
    const float* __restrict__ coef, const float* __restrict__ bias,
    const float* __restrict__ gamma, const float* __restrict__ beta,
    const float* __restrict__ sP, const float* __restrict__ qP,
    float* __restrict__ Out)
{
  __shared__ __align__(16) char smem[32768]; // As 32KB union red 18.4KB
  __shared__ float sc[512], sh[512];
  u16* As = (u16*)smem;
  float* red = (float*)smem;
  int raw = blockIdx.x, nt = raw & 15, mt = raw >> 4;
  int t = threadIdx.x, l = t & 63, e = t >> 6;

  const u16* Bb = Wp + (size_t)(e * 32 + nt * 2) * 16 * 512 + l * 8;
  bf16x8 bfr[2][2];
  #pragma unroll
  for (int n = 0; n < 2; ++n)                // B preload step 0 (issue early)
    bfr[0][n] = *(const bf16x8*)(Bb + (size_t)n * 16 * 512);

  {                                          // BN params: one col per thread
    float S = 0.f, Q = 0.f;
    #pragma unroll
    for (int p = 0; p < 16; ++p) { S += sP[p * 512 + t]; Q += qP[p * 512 + t]; }
    float mean = S * (1.0f / 1024.0f);
    float var  = Q * (1.0f / 1024.0f) - mean * mean;     // biased, matches ref
    float s_ = gamma[t] * rsqrtf(var + 1e-5f);
    sc[t] = s_; sh[t] = beta[t] - mean * s_;
  }
  __syncthreads();

  const u16* hsrc = hb + (size_t)mt * 16384; // this block's 32x512 slab (packed)
  #pragma unroll
  for (int rep = 0; rep < 4; ++rep) {        // BN+ELU transform -> As (linear)
    int ci = rep * 512 + t;
    u16x8 hv = *(const u16x8*)(hsrc + (size_t)ci * 8);
    int s = (ci >> 6) & 15, c = (l >> 4) & 3;
    int k0 = s * 32 + c * 8;
    f32x4 s0 = *(const f32x4*)&sc[k0], s1 = *(const f32x4*)&sc[k0 + 4];
    f32x4 h0 = *(const f32x4*)&sh[k0], h1 = *(const f32x4*)&sh[k0 + 4];
    u16x8 o;
    #pragma unroll
    for (int i = 0; i < 4; ++i) {
      float v = bf2f(hv[i]) * s0[i] + h0[i];
      o[i] = f2bf(v > 0.f ? v : expm1f(v));
    }
    #pragma unroll
    for (int i = 0; i < 4; ++i) {
      float v = bf2f(hv[4 + i]) * s1[i] + h1[i];
      o[4 + i] = f2bf(v > 0.f ? v : expm1f(v));
    }
    *(u16x8*)&As[(size_t)ci * 8] = o;
  }
  __syncthreads();

  f32x4 acc[2][2] = {};
  #pragma unroll
  for (int s = 0; s < 16; ++s) {
    const int cur = s & 1, nxt = cur ^ 1;
    if (s < 15) {
      #pragma unroll
      for (int n = 0; n < 2; ++n)
        bfr[nxt][n] = *(const bf16x8*)(Bb + (size_t)n * 16 * 512 + (s + 1) * 512);
    }
    bf16x8 af[2];
    #pragma unroll
    for (int m = 0; m < 2; ++m)              // A from LDS, lane-linear
      af[m] = *(const bf16x8*)&As[((m * 16 + s) * 64 + l) * 8];
    #pragma unroll
    for (int m = 0; m < 2; ++m)
      #pragma unroll
      for (int n = 0; n < 2; ++n)
        acc[m][n] = __builtin_amdgcn_mfma_f32_16x16x32_bf16(af[m], bfr[cur][n], acc[m][n], 0, 0, 0);
  }
  __syncthreads();                           // As -> red reuse barrier

  int rl = (l >> 4) * 4;
  #pragma unroll
  for (int m = 0; m < 2; ++m)
    #pragma unroll
    for (int r = 0; r < 4; ++r) {
      float cf = coef[(size_t)(mt * 32 + m * 16 + rl + r) * 8 + e];
      #pragma unroll
      for (int n = 0; n < 2; ++n) acc[m][n][r] *= cf;
    }

#define RED_STORE(slot)                                                       \
  { _Pragma("unroll") for (int m = 0; m < 2; ++m)                             \
    _Pragma("unroll") for (int n = 0; n < 2; ++n)                             \
    _Pragma("unroll") for (int r = 0; r < 4; ++r)                             \
      red[(slot) * 1152 + (m * 16 + rl + r) * 36 + n * 16 + (l & 15)] = acc[m][n][r]; }
#define RED_ADD(slot)                                                         \
  { _Pragma("unroll") for (int m = 0; m < 2; ++m)                             \
    _Pragma("unroll") for (int n = 0; n < 2; ++n)                             \
    _Pragma("unroll") for (int r = 0; r < 4; ++r)                             \
      acc[m][n][r] += red[(slot) * 1152 + (m * 16 + rl + r) * 36 + n * 16 + (l & 15)]; }

  if (e >= 4) RED_STORE(e - 4);
  __syncthreads();
  if (e < 4) { RED_ADD(e); RED_STORE(e); }
  __syncthreads();

  if (t < 256) {                             // parallel epilogue -> out
    int row = t >> 3, c0 = (t & 7) * 4;
    f32x4 v = {0.f, 0.f, 0.f, 0.f};
    #pragma unroll
    for (int sl = 0; sl < 4; ++sl)
      v += *(const f32x4*)&red[sl * 1152 + row * 36 + c0];
    int rowg = mt * 32 + row, colg = nt * 32 + c0;
    f32x4 cv0 = *(const f32x4*)(coef + (size_t)rowg * 8);
    f32x4 cv1 = *(const f32x4*)(coef + (size_t)rowg * 8 + 4);
    #pragma unroll
    for (int e2 = 0; e2 < 4; ++e2) {
      v += cv0[e2] * *(const f32x4*)(bias + e2 * 512 + colg);
      v += cv1[e2] * *(const f32x4*)(bias + (e2 + 4) * 512 + colg);
    }
    *(f32x4*)(Out + (size_t)rowg * 512 + colg) = v;
  }
#undef RED_STORE
#undef RED_ADD
}

extern "C" void kernel_launch(void* const* d_in, const int* in_sizes, int n_in,
                              void* d_out, int out_size, void* d_ws, size_t ws_size,
                              hipStream_t stream)
{
  const float* x     = (const float*)d_in[0];
  const float* coef  = (const float*)d_in[1];
  const float* w1    = (const float*)d_in[2];
  const float* b1    = (const float*)d_in[3];
  const float* w2    = (const float*)d_in[4];
  const float* b2    = (const float*)d_in[5];
  const float* gamma = (const float*)d_in[6];
  const float* beta  = (const float*)d_in[7];
  float* out = (float*)d_out;

  char* ws = (char*)d_ws;
  u16* w1p  = (u16*)(ws);                          //  4 MB packed bf16
  u16* w2p  = (u16*)(ws + (4u << 20));             //  4 MB
  u16* xbp  = (u16*)(ws + (8u << 20));             //  1 MB packed bf16
  u16* hb   = (u16*)(ws + (9u << 20));             //  1 MB packed bf16 (pre-BN h)
  float* sP = (float*)(ws + (10u << 20));          // 32 KB [16][512] col sums
  float* qP = (float*)(ws + (10u << 20) + 65536);  // 32 KB [16][512] col sumsq

  prep_kernel<<<1088, 256, 0, stream>>>(x, w1, w2, xbp, w1p, w2p);
  gemm1_kernel<<<256, 512, 0, stream>>>(xbp, w1p, coef, b1, hb, sP, qP);
  gemm2_kernel<<<512, 512, 0, stream>>>(hb, w2p, coef, b2, gamma, beta, sP, qP, out);
}